// Round 1
// baseline (288.104 us; speedup 1.0000x reference)
//
#include <hip/hip_runtime.h>

// EdgeModel: out = leaky_relu(concat(x_s[src], x_t[tgt], edge_attr, u[batch]) @ W1 + b1) @ W2 + b2
// F_XS=10, F_XT=5, F_E=10, F_U=10 -> concat 35, hidden 10, out 10.
//
// Round 6: latency-bound fix -- 4 edges per thread (EPT=4), consecutive layout.
//   Evidence: main kernel 98 us @ 1.83 TB/s (23% peak), VALUBusy 15.6%, VGPR=20.
//   Top-down: per-SIMD issue is only ~13% of cycles -> waves stall in vmcnt on the
//   NT-idx -> L2-gather chain with ~1 edge of MLP per thread. FETCH/WRITE are already
//   at streaming-ideal (97/78 MB), so bytes are done; concurrency is the lever.
//   - Thread t of block b owns edges base..base+3 (base = (b*256+t)*4):
//     idx loads collapse to 3x NT dwordx4; edge_attr is 160 B contiguous, 16B-aligned
//     (10x NT dwordx4); out is 160 B contiguous (10x plain dwordx4 stores).
//   - All loads for 4 edges issue before any FMA -> ~4x loads in flight per wave.
//   - f16 L2-resident gather tables kept from round 5 (FETCH at ideal proves they work).
//   - EPT4 kernel requires E % 4 == 0 (alignment of the edge_index+E column and the
//     160 B groups); otherwise fall back to the round-5 single-edge kernel.

#define F_XS 10
#define F_XT 5
#define F_E  10
#define F_U  10
#define F_IN 35
#define EPT  4

typedef float vf4 __attribute__((ext_vector_type(4)));
typedef float vf2 __attribute__((ext_vector_type(2)));
typedef int   vi4 __attribute__((ext_vector_type(4)));
typedef _Float16 f16;

// ---------------- table conversion pass (runs every call, ~5 us) ----------------
__global__ __launch_bounds__(256) void convert_tables_kernel(
    const float* __restrict__ xs, const float* __restrict__ xt, const float* __restrict__ uu,
    f16* __restrict__ xs_h, f16* __restrict__ xt_h, f16* __restrict__ u_h,
    int n_xs_elems, int n_u_elems, int n_t_rows)
{
    const int tid = blockIdx.x * blockDim.x + threadIdx.x;
    if (tid < n_xs_elems) {
        xs_h[tid] = (f16)xs[tid];
    } else if (tid < n_xs_elems + n_u_elems) {
        const int i = tid - n_xs_elems;
        u_h[i] = (f16)uu[i];
    } else {
        const int r = tid - n_xs_elems - n_u_elems;
        if (r < n_t_rows) {
            const float* p = xt + (long long)r * F_XT;
            f16* q = xt_h + (long long)r * 6;
            #pragma unroll
            for (int i = 0; i < 5; ++i) q[i] = (f16)p[i];
            q[5] = (f16)0.f;
        }
    }
}

// ---------------- shared per-edge math ----------------
__device__ __forceinline__ void compute_edge(
    const f16* __restrict__ s, const f16* __restrict__ t, const f16* __restrict__ uv,
    const float* __restrict__ a,
    const float* __restrict__ W1, const float* __restrict__ b1,
    const float* __restrict__ W2, const float* __restrict__ b2,
    float* __restrict__ o)
{
    float h[F_E];
    #pragma unroll
    for (int j = 0; j < F_E; ++j) h[j] = b1[j];

    #pragma unroll
    for (int k = 0; k < 10; ++k) {          // x_s segment, rows 0..9
        const float x = (float)s[k];
        #pragma unroll
        for (int j = 0; j < F_E; ++j) h[j] = fmaf(x, W1[k * F_E + j], h[j]);
    }
    #pragma unroll
    for (int k = 0; k < 5; ++k) {           // x_t segment, rows 10..14
        const float x = (float)t[k];
        #pragma unroll
        for (int j = 0; j < F_E; ++j) h[j] = fmaf(x, W1[(10 + k) * F_E + j], h[j]);
    }
    #pragma unroll
    for (int k = 0; k < 10; ++k) {          // edge_attr segment, rows 15..24
        const float x = a[k];
        #pragma unroll
        for (int j = 0; j < F_E; ++j) h[j] = fmaf(x, W1[(15 + k) * F_E + j], h[j]);
    }
    #pragma unroll
    for (int k = 0; k < 10; ++k) {          // u segment, rows 25..34
        const float x = (float)uv[k];
        #pragma unroll
        for (int j = 0; j < F_E; ++j) h[j] = fmaf(x, W1[(25 + k) * F_E + j], h[j]);
    }

    #pragma unroll
    for (int j = 0; j < F_E; ++j) h[j] = (h[j] >= 0.0f) ? h[j] : 0.1f * h[j];

    #pragma unroll
    for (int j = 0; j < F_E; ++j) o[j] = b2[j];
    #pragma unroll
    for (int k = 0; k < F_E; ++k) {
        const float x = h[k];
        #pragma unroll
        for (int j = 0; j < F_E; ++j) o[j] = fmaf(x, W2[k * F_E + j], o[j]);
    }
}

// ---------------- main kernel: 4 edges/thread, f16 tables ----------------
__global__ __launch_bounds__(256) void edge_model_f16tab_ept4_kernel(
    const f16*   __restrict__ xs_h,       // [N_S, 10] f16
    const f16*   __restrict__ xt_h,       // [N_T, 6]  f16 (padded)
    const int*   __restrict__ edge_index, // [2, E]
    const float* __restrict__ edge_attr,  // [E, 10]
    const f16*   __restrict__ u_h,        // [B, 10] f16
    const int*   __restrict__ batch_e,    // [E]
    const float* __restrict__ W1,         // [35, 10]
    const float* __restrict__ b1,         // [10]
    const float* __restrict__ W2,         // [10, 10]
    const float* __restrict__ b2,         // [10]
    float*       __restrict__ out,        // [E, 10]
    int E)
{
    const long long base =
        ((long long)blockIdx.x * blockDim.x + threadIdx.x) * (long long)EPT;
    if (base >= E) return;

    if (base + EPT <= E) {
        // ---- phase 1: issue ALL loads for 4 edges before any compute ----
        const vi4 srcs = __builtin_nontemporal_load((const vi4*)(edge_index + base));
        const vi4 tgts = __builtin_nontemporal_load((const vi4*)(edge_index + E + base));
        const vi4 bes  = __builtin_nontemporal_load((const vi4*)(batch_e + base));

        f16 s[EPT][10];
        f16 tt[EPT][8];
        f16 uv[EPT][10];
        #pragma unroll
        for (int i = 0; i < EPT; ++i) {
            const int src = srcs[i];
            const int tgt = tgts[i];
            const int be  = bes[i];
            __builtin_memcpy(s[i],  xs_h + (long long)src * 10, 20); // dwordx4+dword
            __builtin_memcpy(tt[i], xt_h + (long long)tgt * 6, 16);  // dwordx4 (4B slack)
            __builtin_memcpy(uv[i], u_h  + (long long)be  * 10, 20); // dwordx4+dword
        }

        // edge_attr for 4 consecutive edges: 160 B contiguous, 16B-aligned
        const vf4* pa = (const vf4*)(edge_attr + base * F_E);
        float af[4 * F_E];
        #pragma unroll
        for (int q = 0; q < 10; ++q) {
            const vf4 v = __builtin_nontemporal_load(pa + q);
            af[4 * q + 0] = v.x; af[4 * q + 1] = v.y;
            af[4 * q + 2] = v.z; af[4 * q + 3] = v.w;
        }

        // ---- phase 2: compute edges sequentially (loads for later edges in flight) ----
        float of[4 * F_E];
        #pragma unroll
        for (int i = 0; i < EPT; ++i)
            compute_edge(s[i], tt[i], uv[i], af + F_E * i, W1, b1, W2, b2, of + F_E * i);

        // ---- phase 3: 160 B contiguous aligned stores ----
        vf4* po = (vf4*)(out + base * F_E);
        #pragma unroll
        for (int q = 0; q < 10; ++q) {
            vf4 v;
            v.x = of[4 * q + 0]; v.y = of[4 * q + 1];
            v.z = of[4 * q + 2]; v.w = of[4 * q + 3];
            po[q] = v;
        }
    } else {
        // tail (only possible when E % 4 != 0; guarded per edge)
        for (int i = 0; i < EPT; ++i) {
            const long long e = base + i;
            if (e >= E) break;
            const int src = edge_index[e];
            const int tgt = edge_index[E + e];
            const int be  = batch_e[e];
            f16 s1[10], t1[8], u1[10];
            __builtin_memcpy(s1, xs_h + (long long)src * 10, 20);
            __builtin_memcpy(t1, xt_h + (long long)tgt * 6, 16);
            __builtin_memcpy(u1, u_h  + (long long)be  * 10, 20);
            float a1[F_E];
            #pragma unroll
            for (int k = 0; k < F_E; ++k) a1[k] = edge_attr[e * F_E + k];
            float o1[F_E];
            compute_edge(s1, t1, u1, a1, W1, b1, W2, b2, o1);
            #pragma unroll
            for (int j = 0; j < F_E; ++j) out[e * F_E + j] = o1[j];
        }
    }
}

// ---------------- round-5 single-edge kernel (fallback for E % 4 != 0) ----------------
__global__ __launch_bounds__(256) void edge_model_f16tab_kernel(
    const f16*   __restrict__ xs_h, const f16* __restrict__ xt_h,
    const int*   __restrict__ edge_index, const float* __restrict__ edge_attr,
    const f16*   __restrict__ u_h, const int* __restrict__ batch_e,
    const float* __restrict__ W1, const float* __restrict__ b1,
    const float* __restrict__ W2, const float* __restrict__ b2,
    float* __restrict__ out, int E)
{
    const int e = blockIdx.x * blockDim.x + threadIdx.x;
    if (e >= E) return;

    const int src = __builtin_nontemporal_load(edge_index + e);
    const int tgt = __builtin_nontemporal_load(edge_index + E + e);
    const int be  = __builtin_nontemporal_load(batch_e + e);

    f16 s[10];  __builtin_memcpy(s, xs_h + (long long)src * 10, 20);
    f16 t[8];   __builtin_memcpy(t, xt_h + (long long)tgt * 6, 16);
    f16 uv[10]; __builtin_memcpy(uv, u_h + (long long)be * 10, 20);

    const float* pe = edge_attr + (long long)e * F_E;
    vf4 a0 = __builtin_nontemporal_load((const vf4*)(pe));
    vf4 a1 = __builtin_nontemporal_load((const vf4*)(pe + 4));
    vf2 a2 = __builtin_nontemporal_load((const vf2*)(pe + 8));
    float af[F_E] = {a0.x,a0.y,a0.z,a0.w, a1.x,a1.y,a1.z,a1.w, a2.x,a2.y};

    float o[F_E];
    compute_edge(s, t, uv, af, W1, b1, W2, b2, o);

    float* po = out + (long long)e * F_E;
    vf4 w0; w0.x=o[0]; w0.y=o[1]; w0.z=o[2]; w0.w=o[3];
    vf4 w1; w1.x=o[4]; w1.y=o[5]; w1.z=o[6]; w1.w=o[7];
    vf2 w2; w2.x=o[8]; w2.y=o[9];
    *(vf4*)(po)     = w0;
    *(vf4*)(po + 4) = w1;
    *(vf2*)(po + 8) = w2;
}

// ---------------- fallback: f32 path (if ws too small) ----------------
__global__ __launch_bounds__(256) void edge_model_f32_kernel(
    const float* __restrict__ x_s, const float* __restrict__ x_t,
    const int*   __restrict__ edge_index, const float* __restrict__ edge_attr,
    const float* __restrict__ u, const int* __restrict__ batch_e,
    const float* __restrict__ W1, const float* __restrict__ b1,
    const float* __restrict__ W2, const float* __restrict__ b2,
    float* __restrict__ out, int E)
{
    const int e = blockIdx.x * blockDim.x + threadIdx.x;
    if (e >= E) return;
    const int src = __builtin_nontemporal_load(edge_index + e);
    const int tgt = __builtin_nontemporal_load(edge_index + E + e);
    const int be  = __builtin_nontemporal_load(batch_e + e);

    float in[F_IN];
    __builtin_memcpy(in,      x_s + (long long)src * F_XS, 40);
    __builtin_memcpy(in + 10, x_t + (long long)tgt * F_XT, 20);
    const float* pe = edge_attr + (long long)e * F_E;
    vf4 a0 = __builtin_nontemporal_load((const vf4*)(pe));
    vf4 a1 = __builtin_nontemporal_load((const vf4*)(pe + 4));
    vf2 a2 = __builtin_nontemporal_load((const vf2*)(pe + 8));
    in[15]=a0.x; in[16]=a0.y; in[17]=a0.z; in[18]=a0.w;
    in[19]=a1.x; in[20]=a1.y; in[21]=a1.z; in[22]=a1.w;
    in[23]=a2.x; in[24]=a2.y;
    __builtin_memcpy(in + 25, u + (long long)be * F_U, 40);

    float h[F_E];
    #pragma unroll
    for (int j = 0; j < F_E; ++j) h[j] = b1[j];
    #pragma unroll
    for (int k = 0; k < F_IN; ++k) {
        const float a = in[k];
        #pragma unroll
        for (int j = 0; j < F_E; ++j) h[j] = fmaf(a, W1[k * F_E + j], h[j]);
    }
    #pragma unroll
    for (int j = 0; j < F_E; ++j) h[j] = (h[j] >= 0.0f) ? h[j] : 0.1f * h[j];

    float o[F_E];
    #pragma unroll
    for (int j = 0; j < F_E; ++j) o[j] = b2[j];
    #pragma unroll
    for (int k = 0; k < F_E; ++k) {
        const float a = h[k];
        #pragma unroll
        for (int j = 0; j < F_E; ++j) o[j] = fmaf(a, W2[k * F_E + j], o[j]);
    }
    float* po = out + (long long)e * F_E;
    vf4 w0; w0.x=o[0]; w0.y=o[1]; w0.z=o[2]; w0.w=o[3];
    vf4 w1; w1.x=o[4]; w1.y=o[5]; w1.z=o[6]; w1.w=o[7];
    vf2 w2; w2.x=o[8]; w2.y=o[9];
    *(vf4*)(po)     = w0;
    *(vf4*)(po + 4) = w1;
    *(vf2*)(po + 8) = w2;
}

extern "C" void kernel_launch(void* const* d_in, const int* in_sizes, int n_in,
                              void* d_out, int out_size, void* d_ws, size_t ws_size,
                              hipStream_t stream) {
    const float* x_s        = (const float*)d_in[0];
    const float* x_t        = (const float*)d_in[1];
    const int*   edge_index = (const int*)  d_in[2];
    const float* edge_attr  = (const float*)d_in[3];
    const float* u          = (const float*)d_in[4];
    const int*   batch_e    = (const int*)  d_in[5];
    const float* W1         = (const float*)d_in[6];
    const float* b1         = (const float*)d_in[7];
    const float* W2         = (const float*)d_in[8];
    const float* b2         = (const float*)d_in[9];
    float*       out        = (float*)d_out;

    const int E   = in_sizes[5];           // batch_e is [E]
    const int N_S = in_sizes[0] / F_XS;
    const int N_T = in_sizes[1] / F_XT;
    const int Bn  = in_sizes[4] / F_U;

    // ws layout (16B-aligned regions): xs_h [N_S*10 f16] | xt_h [N_T*6 f16 + 16B slack] | u_h [Bn*10 f16]
    const size_t xs_bytes = (size_t)N_S * 10 * sizeof(f16);
    const size_t xs_off   = 0;
    const size_t xt_off   = (xs_off + xs_bytes + 15) & ~(size_t)15;
    const size_t xt_bytes = (size_t)N_T * 6 * sizeof(f16) + 16;  // +16: dwordx4 slack on last row
    const size_t u_off    = (xt_off + xt_bytes + 15) & ~(size_t)15;
    const size_t u_bytes  = (size_t)Bn * 10 * sizeof(f16);
    const size_t need     = u_off + u_bytes;

    const int block = 256;

    if (ws_size >= need) {
        f16* xs_h = (f16*)((char*)d_ws + xs_off);
        f16* xt_h = (f16*)((char*)d_ws + xt_off);
        f16* u_h  = (f16*)((char*)d_ws + u_off);

        const int n_xs = N_S * 10, n_u = Bn * 10;
        const int conv_threads = n_xs + n_u + N_T;
        convert_tables_kernel<<<(conv_threads + block - 1) / block, block, 0, stream>>>(
            x_s, x_t, u, xs_h, xt_h, u_h, n_xs, n_u, N_T);

        if ((E & 3) == 0) {
            const int edges_per_block = block * EPT;
            const int grid_e = (E + edges_per_block - 1) / edges_per_block;
            edge_model_f16tab_ept4_kernel<<<grid_e, block, 0, stream>>>(
                xs_h, xt_h, edge_index, edge_attr, u_h, batch_e, W1, b1, W2, b2, out, E);
        } else {
            const int grid_e = (E + block - 1) / block;
            edge_model_f16tab_kernel<<<grid_e, block, 0, stream>>>(
                xs_h, xt_h, edge_index, edge_attr, u_h, batch_e, W1, b1, W2, b2, out, E);
        }
    } else {
        const int grid_e = (E + block - 1) / block;
        edge_model_f32_kernel<<<grid_e, block, 0, stream>>>(
            x_s, x_t, edge_index, edge_attr, u, batch_e, W1, b1, W2, b2, out, E);
    }
}

// Round 2
// 260.527 us; speedup vs baseline: 1.1058x; 1.1058x over previous
//
#include <hip/hip_runtime.h>

// EdgeModel: out = leaky_relu(concat(x_s[src], x_t[tgt], edge_attr, u[batch]) @ W1 + b1) @ W2 + b2
// F_XS=10, F_XT=5, F_E=10, F_U=10 -> concat 35, hidden 10, out 10.
//
// Round 7: EPT=4 with BLOCK-STRIDED assignment (fixes round-6 regression).
//   Round-6 post-mortem: consecutive-edges-per-thread broke per-instruction
//   coalescing (64 lanes at 160 B stride per dwordx4 -> 64 lines/instr, NT hint
//   dropped the lines before sibling loads reused them) -> FETCH 97->227 MB.
//   BW still rose 1.83->2.2 TB/s, confirming the latency/ILP theory.
//   Fix: thread owns edges {blockBase + i*256 + tid}, i=0..3. Per-instruction
//   lane addresses are consecutive rows (round-5 ideal-FETCH pattern) while each
//   thread still overlaps 4 independent idx->gather->MLP chains.
//   __launch_bounds__(256,4): VGPR cap 128 so the compiler keeps all 4 edges'
//   loads hoisted (round-6's 48-VGPR alloc shows it otherwise sinks them).
//   f16 L2-resident gather tables kept (FETCH at ideal proves they work).

#define F_XS 10
#define F_XT 5
#define F_E  10
#define F_U  10
#define F_IN 35
#define EPT  4
#define BLOCK 256

typedef float vf4 __attribute__((ext_vector_type(4)));
typedef float vf2 __attribute__((ext_vector_type(2)));
typedef _Float16 f16;

// ---------------- table conversion pass (runs every call, ~5 us) ----------------
__global__ __launch_bounds__(256) void convert_tables_kernel(
    const float* __restrict__ xs, const float* __restrict__ xt, const float* __restrict__ uu,
    f16* __restrict__ xs_h, f16* __restrict__ xt_h, f16* __restrict__ u_h,
    int n_xs_elems, int n_u_elems, int n_t_rows)
{
    const int tid = blockIdx.x * blockDim.x + threadIdx.x;
    if (tid < n_xs_elems) {
        xs_h[tid] = (f16)xs[tid];
    } else if (tid < n_xs_elems + n_u_elems) {
        const int i = tid - n_xs_elems;
        u_h[i] = (f16)uu[i];
    } else {
        const int r = tid - n_xs_elems - n_u_elems;
        if (r < n_t_rows) {
            const float* p = xt + (long long)r * F_XT;
            f16* q = xt_h + (long long)r * 6;
            #pragma unroll
            for (int i = 0; i < 5; ++i) q[i] = (f16)p[i];
            q[5] = (f16)0.f;
        }
    }
}

// ---------------- shared per-edge math ----------------
__device__ __forceinline__ void compute_edge(
    const f16* __restrict__ s, const f16* __restrict__ t, const f16* __restrict__ uv,
    const float* __restrict__ a,
    const float* __restrict__ W1, const float* __restrict__ b1,
    const float* __restrict__ W2, const float* __restrict__ b2,
    float* __restrict__ o)
{
    float h[F_E];
    #pragma unroll
    for (int j = 0; j < F_E; ++j) h[j] = b1[j];

    #pragma unroll
    for (int k = 0; k < 10; ++k) {          // x_s segment, rows 0..9
        const float x = (float)s[k];
        #pragma unroll
        for (int j = 0; j < F_E; ++j) h[j] = fmaf(x, W1[k * F_E + j], h[j]);
    }
    #pragma unroll
    for (int k = 0; k < 5; ++k) {           // x_t segment, rows 10..14
        const float x = (float)t[k];
        #pragma unroll
        for (int j = 0; j < F_E; ++j) h[j] = fmaf(x, W1[(10 + k) * F_E + j], h[j]);
    }
    #pragma unroll
    for (int k = 0; k < 10; ++k) {          // edge_attr segment, rows 15..24
        const float x = a[k];
        #pragma unroll
        for (int j = 0; j < F_E; ++j) h[j] = fmaf(x, W1[(15 + k) * F_E + j], h[j]);
    }
    #pragma unroll
    for (int k = 0; k < 10; ++k) {          // u segment, rows 25..34
        const float x = (float)uv[k];
        #pragma unroll
        for (int j = 0; j < F_E; ++j) h[j] = fmaf(x, W1[(25 + k) * F_E + j], h[j]);
    }

    #pragma unroll
    for (int j = 0; j < F_E; ++j) h[j] = (h[j] >= 0.0f) ? h[j] : 0.1f * h[j];

    #pragma unroll
    for (int j = 0; j < F_E; ++j) o[j] = b2[j];
    #pragma unroll
    for (int k = 0; k < F_E; ++k) {
        const float x = h[k];
        #pragma unroll
        for (int j = 0; j < F_E; ++j) o[j] = fmaf(x, W2[k * F_E + j], o[j]);
    }
}

// ---------------- main kernel: 4 edges/thread, block-strided, f16 tables ----------------
__global__ __launch_bounds__(256, 4) void edge_model_f16tab_ept4s_kernel(
    const f16*   __restrict__ xs_h,       // [N_S, 10] f16
    const f16*   __restrict__ xt_h,       // [N_T, 6]  f16 (padded)
    const int*   __restrict__ edge_index, // [2, E]
    const float* __restrict__ edge_attr,  // [E, 10]
    const f16*   __restrict__ u_h,        // [B, 10] f16
    const int*   __restrict__ batch_e,    // [E]
    const float* __restrict__ W1,         // [35, 10]
    const float* __restrict__ b1,         // [10]
    const float* __restrict__ W2,         // [10, 10]
    const float* __restrict__ b2,         // [10]
    float*       __restrict__ out,        // [E, 10]
    int E)
{
    const int tid = threadIdx.x;
    const long long blockBase = (long long)blockIdx.x * (BLOCK * EPT);

    if (blockBase + BLOCK * EPT <= E) {
        // -------- full block fast path --------
        long long e[EPT];
        #pragma unroll
        for (int i = 0; i < EPT; ++i) e[i] = blockBase + i * BLOCK + tid;

        // phase 1: all index loads (coalesced NT dwords), 12 in flight
        int src[EPT], tgt[EPT], be[EPT];
        #pragma unroll
        for (int i = 0; i < EPT; ++i) {
            src[i] = __builtin_nontemporal_load(edge_index + e[i]);
            tgt[i] = __builtin_nontemporal_load(edge_index + E + e[i]);
            be[i]  = __builtin_nontemporal_load(batch_e + e[i]);
        }

        // phase 2: all gathers (L2-resident f16 tables) + all edge_attr rows
        f16 s[EPT][10];
        f16 tt[EPT][8];
        f16 uv[EPT][10];
        float af[EPT][F_E];
        #pragma unroll
        for (int i = 0; i < EPT; ++i) {
            __builtin_memcpy(s[i],  xs_h + (long long)src[i] * 10, 20); // dwordx4+dword
            __builtin_memcpy(tt[i], xt_h + (long long)tgt[i] * 6, 16);  // dwordx4 (4B slack)
            __builtin_memcpy(uv[i], u_h  + (long long)be[i]  * 10, 20); // dwordx4+dword
        }
        #pragma unroll
        for (int i = 0; i < EPT; ++i) {
            const float* pe = edge_attr + e[i] * F_E;
            const vf4 a0 = __builtin_nontemporal_load((const vf4*)(pe));
            const vf4 a1 = __builtin_nontemporal_load((const vf4*)(pe + 4));
            const vf2 a2 = __builtin_nontemporal_load((const vf2*)(pe + 8));
            af[i][0]=a0.x; af[i][1]=a0.y; af[i][2]=a0.z; af[i][3]=a0.w;
            af[i][4]=a1.x; af[i][5]=a1.y; af[i][6]=a1.z; af[i][7]=a1.w;
            af[i][8]=a2.x; af[i][9]=a2.y;
        }

        // phase 3: compute edge i (later edges' loads still in flight), store coalesced
        #pragma unroll
        for (int i = 0; i < EPT; ++i) {
            float o[F_E];
            compute_edge(s[i], tt[i], uv[i], af[i], W1, b1, W2, b2, o);
            float* po = out + e[i] * F_E;
            vf4 w0; w0.x=o[0]; w0.y=o[1]; w0.z=o[2]; w0.w=o[3];
            vf4 w1; w1.x=o[4]; w1.y=o[5]; w1.z=o[6]; w1.w=o[7];
            vf2 w2; w2.x=o[8]; w2.y=o[9];
            *(vf4*)(po)     = w0;
            *(vf4*)(po + 4) = w1;
            *(vf2*)(po + 8) = w2;
        }
    } else {
        // -------- tail block: per-edge guard --------
        #pragma unroll
        for (int i = 0; i < EPT; ++i) {
            const long long e = blockBase + i * BLOCK + tid;
            if (e >= E) continue;
            const int src = edge_index[e];
            const int tgt = edge_index[E + e];
            const int be  = batch_e[e];
            f16 s1[10], t1[8], u1[10];
            __builtin_memcpy(s1, xs_h + (long long)src * 10, 20);
            __builtin_memcpy(t1, xt_h + (long long)tgt * 6, 16);
            __builtin_memcpy(u1, u_h  + (long long)be  * 10, 20);
            float a1[F_E];
            #pragma unroll
            for (int k = 0; k < F_E; ++k) a1[k] = edge_attr[e * F_E + k];
            float o1[F_E];
            compute_edge(s1, t1, u1, a1, W1, b1, W2, b2, o1);
            #pragma unroll
            for (int j = 0; j < F_E; ++j) out[e * F_E + j] = o1[j];
        }
    }
}

// ---------------- fallback: f32 path (if ws too small) ----------------
__global__ __launch_bounds__(256) void edge_model_f32_kernel(
    const float* __restrict__ x_s, const float* __restrict__ x_t,
    const int*   __restrict__ edge_index, const float* __restrict__ edge_attr,
    const float* __restrict__ u, const int* __restrict__ batch_e,
    const float* __restrict__ W1, const float* __restrict__ b1,
    const float* __restrict__ W2, const float* __restrict__ b2,
    float* __restrict__ out, int E)
{
    const int e = blockIdx.x * blockDim.x + threadIdx.x;
    if (e >= E) return;
    const int src = __builtin_nontemporal_load(edge_index + e);
    const int tgt = __builtin_nontemporal_load(edge_index + E + e);
    const int be  = __builtin_nontemporal_load(batch_e + e);

    float in[F_IN];
    __builtin_memcpy(in,      x_s + (long long)src * F_XS, 40);
    __builtin_memcpy(in + 10, x_t + (long long)tgt * F_XT, 20);
    const float* pe = edge_attr + (long long)e * F_E;
    vf4 a0 = __builtin_nontemporal_load((const vf4*)(pe));
    vf4 a1 = __builtin_nontemporal_load((const vf4*)(pe + 4));
    vf2 a2 = __builtin_nontemporal_load((const vf2*)(pe + 8));
    in[15]=a0.x; in[16]=a0.y; in[17]=a0.z; in[18]=a0.w;
    in[19]=a1.x; in[20]=a1.y; in[21]=a1.z; in[22]=a1.w;
    in[23]=a2.x; in[24]=a2.y;
    __builtin_memcpy(in + 25, u + (long long)be * F_U, 40);

    float h[F_E];
    #pragma unroll
    for (int j = 0; j < F_E; ++j) h[j] = b1[j];
    #pragma unroll
    for (int k = 0; k < F_IN; ++k) {
        const float a = in[k];
        #pragma unroll
        for (int j = 0; j < F_E; ++j) h[j] = fmaf(a, W1[k * F_E + j], h[j]);
    }
    #pragma unroll
    for (int j = 0; j < F_E; ++j) h[j] = (h[j] >= 0.0f) ? h[j] : 0.1f * h[j];

    float o[F_E];
    #pragma unroll
    for (int j = 0; j < F_E; ++j) o[j] = b2[j];
    #pragma unroll
    for (int k = 0; k < F_E; ++k) {
        const float a = h[k];
        #pragma unroll
        for (int j = 0; j < F_E; ++j) o[j] = fmaf(a, W2[k * F_E + j], o[j]);
    }
    float* po = out + (long long)e * F_E;
    vf4 w0; w0.x=o[0]; w0.y=o[1]; w0.z=o[2]; w0.w=o[3];
    vf4 w1; w1.x=o[4]; w1.y=o[5]; w1.z=o[6]; w1.w=o[7];
    vf2 w2; w2.x=o[8]; w2.y=o[9];
    *(vf4*)(po)     = w0;
    *(vf4*)(po + 4) = w1;
    *(vf2*)(po + 8) = w2;
}

extern "C" void kernel_launch(void* const* d_in, const int* in_sizes, int n_in,
                              void* d_out, int out_size, void* d_ws, size_t ws_size,
                              hipStream_t stream) {
    const float* x_s        = (const float*)d_in[0];
    const float* x_t        = (const float*)d_in[1];
    const int*   edge_index = (const int*)  d_in[2];
    const float* edge_attr  = (const float*)d_in[3];
    const float* u          = (const float*)d_in[4];
    const int*   batch_e    = (const int*)  d_in[5];
    const float* W1         = (const float*)d_in[6];
    const float* b1         = (const float*)d_in[7];
    const float* W2         = (const float*)d_in[8];
    const float* b2         = (const float*)d_in[9];
    float*       out        = (float*)d_out;

    const int E   = in_sizes[5];           // batch_e is [E]
    const int N_S = in_sizes[0] / F_XS;
    const int N_T = in_sizes[1] / F_XT;
    const int Bn  = in_sizes[4] / F_U;

    // ws layout (16B-aligned regions): xs_h [N_S*10 f16] | xt_h [N_T*6 f16 + 16B slack] | u_h [Bn*10 f16]
    const size_t xs_bytes = (size_t)N_S * 10 * sizeof(f16);
    const size_t xs_off   = 0;
    const size_t xt_off   = (xs_off + xs_bytes + 15) & ~(size_t)15;
    const size_t xt_bytes = (size_t)N_T * 6 * sizeof(f16) + 16;  // +16: dwordx4 slack on last row
    const size_t u_off    = (xt_off + xt_bytes + 15) & ~(size_t)15;
    const size_t u_bytes  = (size_t)Bn * 10 * sizeof(f16);
    const size_t need     = u_off + u_bytes;

    const int block = BLOCK;

    if (ws_size >= need) {
        f16* xs_h = (f16*)((char*)d_ws + xs_off);
        f16* xt_h = (f16*)((char*)d_ws + xt_off);
        f16* u_h  = (f16*)((char*)d_ws + u_off);

        const int n_xs = N_S * 10, n_u = Bn * 10;
        const int conv_threads = n_xs + n_u + N_T;
        convert_tables_kernel<<<(conv_threads + block - 1) / block, block, 0, stream>>>(
            x_s, x_t, u, xs_h, xt_h, u_h, n_xs, n_u, N_T);

        const int edges_per_block = block * EPT;
        const int grid_e = (E + edges_per_block - 1) / edges_per_block;
        edge_model_f16tab_ept4s_kernel<<<grid_e, block, 0, stream>>>(
            xs_h, xt_h, edge_index, edge_attr, u_h, batch_e, W1, b1, W2, b2, out, E);
    } else {
        const int grid_e = (E + block - 1) / block;
        edge_model_f32_kernel<<<grid_e, block, 0, stream>>>(
            x_s, x_t, edge_index, edge_attr, u, batch_e, W1, b1, W2, b2, out, E);
    }
}

// Round 3
// 204.960 us; speedup vs baseline: 1.4057x; 1.2711x over previous
//
#include <hip/hip_runtime.h>

// EdgeModel: out = leaky_relu(concat(x_s[src], x_t[tgt], edge_attr, u[batch]) @ W1 + b1) @ W2 + b2
// F_XS=10, F_XT=5, F_E=10, F_U=10 -> concat 35, hidden 10, out 10.
//
// Round 8: LDS-staged streams, EPT=1 (reverts both EPT4 experiments).
//   Cross-round evidence: R0 (EPT1) 98us ideal bytes; EPT4 variants raise FETCH
//   (155-227 MiB) + drop occupancy -> worse. R0's binder is NOT bytes (23% HBM),
//   NOT VALU (16%), NOT L2: waves wait ~38k cyc vs ~2-3k chain latency ->
//   memory-request occupancy: 40B-lane-stride attr loads/stores act divergent
//   (~40 lines/instr) and clog the per-CU TA/miss queue alongside the 5 true gathers.
//   Fix: dense full-line cooperative loads/stores through LDS; per-thread row access
//   moves to LDS (2-way bank alias = free). Only the 3-table gathers stay divergent,
//   issued early so their latency hides under attr staging.
//   - idx: t<192 one NT dwordx4 each (src|tgt|be thirds; wave-uniform split).
//   - attr: 640 x4 slots; thread does slots {tid, tid+256, tid+512<640}.
//   - out: per-thread row -> LDS -> cooperative dense dwordx4 stores (full lines).
//   - f16 L2-resident gather tables kept (absmax 0.03125 passed 3 rounds).
//   - fast path needs E%4==0 (tgt column x4 alignment) else round-5 fallback.

#define F_XS 10
#define F_XT 5
#define F_E  10
#define F_U  10
#define F_IN 35
#define BLOCK 256

typedef float vf4 __attribute__((ext_vector_type(4)));
typedef float vf2 __attribute__((ext_vector_type(2)));
typedef int   vi4 __attribute__((ext_vector_type(4)));
typedef _Float16 f16;

// ---------------- table conversion pass (runs every call, ~5 us) ----------------
__global__ __launch_bounds__(256) void convert_tables_kernel(
    const float* __restrict__ xs, const float* __restrict__ xt, const float* __restrict__ uu,
    f16* __restrict__ xs_h, f16* __restrict__ xt_h, f16* __restrict__ u_h,
    int n_xs_elems, int n_u_elems, int n_t_rows)
{
    const int tid = blockIdx.x * blockDim.x + threadIdx.x;
    if (tid < n_xs_elems) {
        xs_h[tid] = (f16)xs[tid];
    } else if (tid < n_xs_elems + n_u_elems) {
        const int i = tid - n_xs_elems;
        u_h[i] = (f16)uu[i];
    } else {
        const int r = tid - n_xs_elems - n_u_elems;
        if (r < n_t_rows) {
            const float* p = xt + (long long)r * F_XT;
            f16* q = xt_h + (long long)r * 6;
            #pragma unroll
            for (int i = 0; i < 5; ++i) q[i] = (f16)p[i];
            q[5] = (f16)0.f;
        }
    }
}

// ---------------- shared per-edge math ----------------
__device__ __forceinline__ void compute_edge(
    const f16* __restrict__ s, const f16* __restrict__ t, const f16* __restrict__ uv,
    const float* __restrict__ a,
    const float* __restrict__ W1, const float* __restrict__ b1,
    const float* __restrict__ W2, const float* __restrict__ b2,
    float* __restrict__ o)
{
    float h[F_E];
    #pragma unroll
    for (int j = 0; j < F_E; ++j) h[j] = b1[j];

    #pragma unroll
    for (int k = 0; k < 10; ++k) {          // x_s segment, rows 0..9
        const float x = (float)s[k];
        #pragma unroll
        for (int j = 0; j < F_E; ++j) h[j] = fmaf(x, W1[k * F_E + j], h[j]);
    }
    #pragma unroll
    for (int k = 0; k < 5; ++k) {           // x_t segment, rows 10..14
        const float x = (float)t[k];
        #pragma unroll
        for (int j = 0; j < F_E; ++j) h[j] = fmaf(x, W1[(10 + k) * F_E + j], h[j]);
    }
    #pragma unroll
    for (int k = 0; k < 10; ++k) {          // edge_attr segment, rows 15..24
        const float x = a[k];
        #pragma unroll
        for (int j = 0; j < F_E; ++j) h[j] = fmaf(x, W1[(15 + k) * F_E + j], h[j]);
    }
    #pragma unroll
    for (int k = 0; k < 10; ++k) {          // u segment, rows 25..34
        const float x = (float)uv[k];
        #pragma unroll
        for (int j = 0; j < F_E; ++j) h[j] = fmaf(x, W1[(25 + k) * F_E + j], h[j]);
    }

    #pragma unroll
    for (int j = 0; j < F_E; ++j) h[j] = (h[j] >= 0.0f) ? h[j] : 0.1f * h[j];

    #pragma unroll
    for (int j = 0; j < F_E; ++j) o[j] = b2[j];
    #pragma unroll
    for (int k = 0; k < F_E; ++k) {
        const float x = h[k];
        #pragma unroll
        for (int j = 0; j < F_E; ++j) o[j] = fmaf(x, W2[k * F_E + j], o[j]);
    }
}

// ---------------- main kernel: LDS-staged streams, f16 gather tables ----------------
__global__ __launch_bounds__(256, 6) void edge_model_lds_kernel(
    const f16*   __restrict__ xs_h,       // [N_S, 10] f16
    const f16*   __restrict__ xt_h,       // [N_T, 6]  f16 (padded)
    const int*   __restrict__ edge_index, // [2, E]
    const float* __restrict__ edge_attr,  // [E, 10]
    const f16*   __restrict__ u_h,        // [B, 10] f16
    const int*   __restrict__ batch_e,    // [E]
    const float* __restrict__ W1,         // [35, 10]
    const float* __restrict__ b1,         // [10]
    const float* __restrict__ W2,         // [10, 10]
    const float* __restrict__ b2,         // [10]
    float*       __restrict__ out,        // [E, 10]
    int E)
{
    __shared__ __align__(16) int   idx_lds[3 * BLOCK];    // 3072 B: src|tgt|be
    __shared__ __align__(16) float row_lds[10 * BLOCK];   // 10240 B: attr rows, reused for out rows

    const int tid = threadIdx.x;
    const long long blockBase = (long long)blockIdx.x * BLOCK;

    if (blockBase + BLOCK <= E) {
        // ---- phase A: issue idx cooperative load FIRST (critical chain root) ----
        vi4 idxv;
        if (tid < 192) {
            const int* p;
            if (tid < 64)       p = edge_index + blockBase + 4 * tid;              // src
            else if (tid < 128) p = edge_index + E + blockBase + 4 * (tid - 64);   // tgt (E%4==0)
            else                p = batch_e + blockBase + 4 * (tid - 128);         // be
            idxv = __builtin_nontemporal_load((const vi4*)p);
        }

        // ---- phase B: issue dense attr loads (independent; stay in flight) ----
        const vf4* pa = (const vf4*)(edge_attr + blockBase * F_E);   // 640 x4 slots
        vf4 A0 = __builtin_nontemporal_load(pa + tid);
        vf4 A1 = __builtin_nontemporal_load(pa + tid + 256);
        vf4 A2;
        if (tid < 128) A2 = __builtin_nontemporal_load(pa + tid + 512);

        // ---- stage idx (waits only the idx load; attr stays outstanding) ----
        if (tid < 192) *(vi4*)(idx_lds + 4 * tid) = idxv;
        __syncthreads();

        const int src = idx_lds[tid];
        const int tgt = idx_lds[256 + tid];
        const int be  = idx_lds[512 + tid];

        // ---- issue divergent gathers EARLY (latency hides under staging) ----
        f16 s[10];  __builtin_memcpy(s,  xs_h + (long long)src * 10, 20);
        f16 tt[8];  __builtin_memcpy(tt, xt_h + (long long)tgt * 6, 16);
        f16 uv[10]; __builtin_memcpy(uv, u_h  + (long long)be  * 10, 20);

        // ---- stage attr rows (waits attr regs; gathers stay outstanding) ----
        *(vf4*)(row_lds + 4 * tid)         = A0;
        *(vf4*)(row_lds + 4 * (tid + 256)) = A1;
        if (tid < 128) *(vf4*)(row_lds + 4 * (tid + 512)) = A2;
        __syncthreads();

        // ---- own attr row: 5x ds_read_b64, stride 10 words (2-way alias = free) ----
        float af[F_E];
        #pragma unroll
        for (int q = 0; q < 5; ++q) {
            const vf2 v = *(const vf2*)(row_lds + 10 * tid + 2 * q);
            af[2 * q]     = v.x;
            af[2 * q + 1] = v.y;
        }

        // ---- MLP (gathers drained here) ----
        float o[F_E];
        compute_edge(s, tt, uv, af, W1, b1, W2, b2, o);

        // ---- own out row -> LDS (same words this thread just read: safe) ----
        #pragma unroll
        for (int q = 0; q < 5; ++q) {
            vf2 v; v.x = o[2 * q]; v.y = o[2 * q + 1];
            *(vf2*)(row_lds + 10 * tid + 2 * q) = v;
        }
        __syncthreads();

        // ---- cooperative dense stores: full 64B lines per instruction ----
        float* po = out + blockBase * F_E;
        *(vf4*)(po + 4 * tid)         = *(const vf4*)(row_lds + 4 * tid);
        *(vf4*)(po + 4 * (tid + 256)) = *(const vf4*)(row_lds + 4 * (tid + 256));
        if (tid < 128)
            *(vf4*)(po + 4 * (tid + 512)) = *(const vf4*)(row_lds + 4 * (tid + 512));
    } else {
        // ---- tail block (block-uniform branch; no barriers here) ----
        const long long e = blockBase + tid;
        if (e < E) {
            const int src = edge_index[e];
            const int tgt = edge_index[E + e];
            const int be  = batch_e[e];
            f16 s1[10], t1[8], u1[10];
            __builtin_memcpy(s1, xs_h + (long long)src * 10, 20);
            __builtin_memcpy(t1, xt_h + (long long)tgt * 6, 16);
            __builtin_memcpy(u1, u_h  + (long long)be  * 10, 20);
            float a1[F_E];
            #pragma unroll
            for (int k = 0; k < F_E; ++k) a1[k] = edge_attr[e * F_E + k];
            float o1[F_E];
            compute_edge(s1, t1, u1, a1, W1, b1, W2, b2, o1);
            #pragma unroll
            for (int j = 0; j < F_E; ++j) out[e * F_E + j] = o1[j];
        }
    }
}

// ---------------- round-5 single-edge kernel (fallback for E % 4 != 0) ----------------
__global__ __launch_bounds__(256) void edge_model_f16tab_kernel(
    const f16*   __restrict__ xs_h, const f16* __restrict__ xt_h,
    const int*   __restrict__ edge_index, const float* __restrict__ edge_attr,
    const f16*   __restrict__ u_h, const int* __restrict__ batch_e,
    const float* __restrict__ W1, const float* __restrict__ b1,
    const float* __restrict__ W2, const float* __restrict__ b2,
    float* __restrict__ out, int E)
{
    const int e = blockIdx.x * blockDim.x + threadIdx.x;
    if (e >= E) return;

    const int src = __builtin_nontemporal_load(edge_index + e);
    const int tgt = __builtin_nontemporal_load(edge_index + E + e);
    const int be  = __builtin_nontemporal_load(batch_e + e);

    f16 s[10];  __builtin_memcpy(s, xs_h + (long long)src * 10, 20);
    f16 t[8];   __builtin_memcpy(t, xt_h + (long long)tgt * 6, 16);
    f16 uv[10]; __builtin_memcpy(uv, u_h + (long long)be * 10, 20);

    const float* pe = edge_attr + (long long)e * F_E;
    vf4 a0 = __builtin_nontemporal_load((const vf4*)(pe));
    vf4 a1 = __builtin_nontemporal_load((const vf4*)(pe + 4));
    vf2 a2 = __builtin_nontemporal_load((const vf2*)(pe + 8));
    float af[F_E] = {a0.x,a0.y,a0.z,a0.w, a1.x,a1.y,a1.z,a1.w, a2.x,a2.y};

    float o[F_E];
    compute_edge(s, t, uv, af, W1, b1, W2, b2, o);

    float* po = out + (long long)e * F_E;
    vf4 w0; w0.x=o[0]; w0.y=o[1]; w0.z=o[2]; w0.w=o[3];
    vf4 w1; w1.x=o[4]; w1.y=o[5]; w1.z=o[6]; w1.w=o[7];
    vf2 w2; w2.x=o[8]; w2.y=o[9];
    *(vf4*)(po)     = w0;
    *(vf4*)(po + 4) = w1;
    *(vf2*)(po + 8) = w2;
}

// ---------------- fallback: f32 path (if ws too small) ----------------
__global__ __launch_bounds__(256) void edge_model_f32_kernel(
    const float* __restrict__ x_s, const float* __restrict__ x_t,
    const int*   __restrict__ edge_index, const float* __restrict__ edge_attr,
    const float* __restrict__ u, const int* __restrict__ batch_e,
    const float* __restrict__ W1, const float* __restrict__ b1,
    const float* __restrict__ W2, const float* __restrict__ b2,
    float* __restrict__ out, int E)
{
    const int e = blockIdx.x * blockDim.x + threadIdx.x;
    if (e >= E) return;
    const int src = __builtin_nontemporal_load(edge_index + e);
    const int tgt = __builtin_nontemporal_load(edge_index + E + e);
    const int be  = __builtin_nontemporal_load(batch_e + e);

    float in[F_IN];
    __builtin_memcpy(in,      x_s + (long long)src * F_XS, 40);
    __builtin_memcpy(in + 10, x_t + (long long)tgt * F_XT, 20);
    const float* pe = edge_attr + (long long)e * F_E;
    vf4 a0 = __builtin_nontemporal_load((const vf4*)(pe));
    vf4 a1 = __builtin_nontemporal_load((const vf4*)(pe + 4));
    vf2 a2 = __builtin_nontemporal_load((const vf2*)(pe + 8));
    in[15]=a0.x; in[16]=a0.y; in[17]=a0.z; in[18]=a0.w;
    in[19]=a1.x; in[20]=a1.y; in[21]=a1.z; in[22]=a1.w;
    in[23]=a2.x; in[24]=a2.y;
    __builtin_memcpy(in + 25, u + (long long)be * F_U, 40);

    float h[F_E];
    #pragma unroll
    for (int j = 0; j < F_E; ++j) h[j] = b1[j];
    #pragma unroll
    for (int k = 0; k < F_IN; ++k) {
        const float a = in[k];
        #pragma unroll
        for (int j = 0; j < F_E; ++j) h[j] = fmaf(a, W1[k * F_E + j], h[j]);
    }
    #pragma unroll
    for (int j = 0; j < F_E; ++j) h[j] = (h[j] >= 0.0f) ? h[j] : 0.1f * h[j];

    float o[F_E];
    #pragma unroll
    for (int j = 0; j < F_E; ++j) o[j] = b2[j];
    #pragma unroll
    for (int k = 0; k < F_E; ++k) {
        const float a = h[k];
        #pragma unroll
        for (int j = 0; j < F_E; ++j) o[j] = fmaf(a, W2[k * F_E + j], o[j]);
    }
    float* po = out + (long long)e * F_E;
    vf4 w0; w0.x=o[0]; w0.y=o[1]; w0.z=o[2]; w0.w=o[3];
    vf4 w1; w1.x=o[4]; w1.y=o[5]; w1.z=o[6]; w1.w=o[7];
    vf2 w2; w2.x=o[8]; w2.y=o[9];
    *(vf4*)(po)     = w0;
    *(vf4*)(po + 4) = w1;
    *(vf2*)(po + 8) = w2;
}

extern "C" void kernel_launch(void* const* d_in, const int* in_sizes, int n_in,
                              void* d_out, int out_size, void* d_ws, size_t ws_size,
                              hipStream_t stream) {
    const float* x_s        = (const float*)d_in[0];
    const float* x_t        = (const float*)d_in[1];
    const int*   edge_index = (const int*)  d_in[2];
    const float* edge_attr  = (const float*)d_in[3];
    const float* u          = (const float*)d_in[4];
    const int*   batch_e    = (const int*)  d_in[5];
    const float* W1         = (const float*)d_in[6];
    const float* b1         = (const float*)d_in[7];
    const float* W2         = (const float*)d_in[8];
    const float* b2         = (const float*)d_in[9];
    float*       out        = (float*)d_out;

    const int E   = in_sizes[5];           // batch_e is [E]
    const int N_S = in_sizes[0] / F_XS;
    const int N_T = in_sizes[1] / F_XT;
    const int Bn  = in_sizes[4] / F_U;

    // ws layout (16B-aligned regions): xs_h [N_S*10 f16] | xt_h [N_T*6 f16 + 16B slack] | u_h [Bn*10 f16]
    const size_t xs_bytes = (size_t)N_S * 10 * sizeof(f16);
    const size_t xs_off   = 0;
    const size_t xt_off   = (xs_off + xs_bytes + 15) & ~(size_t)15;
    const size_t xt_bytes = (size_t)N_T * 6 * sizeof(f16) + 16;  // +16: dwordx4 slack on last row
    const size_t u_off    = (xt_off + xt_bytes + 15) & ~(size_t)15;
    const size_t u_bytes  = (size_t)Bn * 10 * sizeof(f16);
    const size_t need     = u_off + u_bytes;

    const int block = BLOCK;

    if (ws_size >= need) {
        f16* xs_h = (f16*)((char*)d_ws + xs_off);
        f16* xt_h = (f16*)((char*)d_ws + xt_off);
        f16* u_h  = (f16*)((char*)d_ws + u_off);

        const int n_xs = N_S * 10, n_u = Bn * 10;
        const int conv_threads = n_xs + n_u + N_T;
        convert_tables_kernel<<<(conv_threads + block - 1) / block, block, 0, stream>>>(
            x_s, x_t, u, xs_h, xt_h, u_h, n_xs, n_u, N_T);

        const int grid_e = (E + block - 1) / block;
        if ((E & 3) == 0) {
            edge_model_lds_kernel<<<grid_e, block, 0, stream>>>(
                xs_h, xt_h, edge_index, edge_attr, u_h, batch_e, W1, b1, W2, b2, out, E);
        } else {
            edge_model_f16tab_kernel<<<grid_e, block, 0, stream>>>(
                xs_h, xt_h, edge_index, edge_attr, u_h, batch_e, W1, b1, W2, b2, out, E);
        }
    } else {
        const int grid_e = (E + block - 1) / block;
        edge_model_f32_kernel<<<grid_e, block, 0, stream>>>(
            x_s, x_t, edge_index, edge_attr, u, batch_e, W1, b1, W2, b2, out, E);
    }
}